// Round 4
// baseline (8906.696 us; speedup 1.0000x reference)
//
#include <hip/hip_runtime.h>

// AugmentedLstm: B=16, T=2048, D=H=512.
// 64 persistent WGs x 256 threads. No grid barrier: h' published as packed
// u64 agent-scope relaxed atomics {2 x f16, u32 step-tag}. Round 4: consumers
// spin on a 64-entry per-WG FLAG array (one coalesced 512B load per wave per
// round — 64x less IC traffic than re-reading the 32KB data buffer, which was
// self-contending at the coherence point), then do ONE tagged-data round;
// embedded tags still verify (flag may race ahead of data; rare respin).
//
// Math: g = (x_t + h)@Wt[:, :5H] + 2b  (pi and ps share W)
//       pi5 = (x+h)@W5 - h@W5 + b5     (highway input)

#define NG 64
#define BLK 256
#define BB 16
#define TT 2048
#define DD 512
#define HHH 512
#define CC 8

typedef _Float16 f16;
typedef _Float16 f16x4 __attribute__((ext_vector_type(4)));
typedef _Float16 f16x8 __attribute__((ext_vector_type(8)));
typedef float f32x4 __attribute__((ext_vector_type(4)));
typedef unsigned long long u64;

__device__ __forceinline__ float sigf(float v) {
  return 1.0f / (1.0f + __expf(-v));
}
__device__ __forceinline__ float tanhfast(float v) {
  return 2.0f / (1.0f + __expf(-2.0f * v)) - 1.0f;
}

__device__ __forceinline__ f16 h_lo(u64 w) {
  return __builtin_bit_cast(f16, (unsigned short)(w & 0xffffu));
}
__device__ __forceinline__ f16 h_hi(u64 w) {
  return __builtin_bit_cast(f16, (unsigned short)((w >> 16) & 0xffffu));
}

__global__ __launch_bounds__(BLK, 1) void lstm_scan(
    const float* __restrict__ x, const int* __restrict__ lengths,
    const float* __restrict__ W, const float* __restrict__ bias,
    float* __restrict__ out, u64* __restrict__ hex /* [2][16][256] tagged */,
    unsigned* __restrict__ flags /* [NG] monotonic step flags */) {
  __shared__ f16 u_sw[BB * DD];        // u = x+h, swizzled A-frag order
  __shared__ f16 h_sw[BB * DD];        // h alone (for h@W5)
  __shared__ float gbuf[4 * 16 * 17];  // per-tile MFMA results
  __shared__ float cbuf[BB * CC];      // cell state

  const int tid = threadIdx.x;
  const int wg = blockIdx.x;
  const int wave = tid >> 6;
  const int lane = tid & 63;
  const int q = lane >> 4;
  const int n16 = lane & 15;

  // ---- Weight B-fragments in registers (loaded once).
  // Tiles 0..2: A=u, 16 cols = gates {0,1},{2,3},{4,5} x 8 cols.
  // Tile  3   : A=h, cols 0..7 = gate-5 rows (h@W5), cols 8..15 zero.
  f16x8 bW[16];
  {
    int grow = 0;
    bool valid = true;
    if (wave < 3) {
      int gate = 2 * wave + (n16 >> 3);
      grow = gate * HHH + wg * CC + (n16 & 7);
    } else if (n16 < 8) {
      grow = 5 * HHH + wg * CC + n16;
    } else {
      valid = false;
    }
    const float* wr = W + (size_t)grow * DD;
#pragma unroll
    for (int kk = 0; kk < 16; ++kk) {
      f16x8 v;
      if (valid) {
        const float* p = wr + kk * 32 + q * 8;
#pragma unroll
        for (int j = 0; j < 8; ++j) v[j] = (f16)p[j];
      } else {
#pragma unroll
        for (int j = 0; j < 8; ++j) v[j] = (f16)0.0f;
      }
      bW[kk] = v;
    }
  }

  // ---- Staging indices. Thread's i-th chunk = cols k..k+3 of row m of the
  // flat [16][512] matrix. LDS granule (8 f16): logical (kk*64 + L),
  // physical (kk*64 + (L ^ kk)) — XOR swizzle keeps ds_write at the 4-way
  // floor and ds_read_b128 conflict-free.
  int soffv[8], pidx[8];
  size_t xcm[8];
#pragma unroll
  for (int i = 0; i < 8; ++i) {
    int e = (tid + i * BLK) * 4;
    int m = e >> 9;
    int k = e & 511;
    pidx[i] = m * 256 + (k >> 1);      // u64 pair index (k multiple of 4)
    xcm[i] = (size_t)m * TT * DD + k;  // x[b=m][t][k] base
    int kk = k >> 5, qq = (k >> 3) & 3, j0 = k & 7;
    int L = qq * 16 + m;
    soffv[i] = (kk * 64 + (L ^ kk)) * 8 + j0;
  }

  // ---- Epilogue constants (threads 0..127: b = tid>>3, n = tid&7).
  const int eb = tid >> 3;
  const int en = tid & 7;
  float bb0 = 0, bb1 = 0, bb2 = 0, bb3 = 0, bb4 = 0, bb5 = 0;
  int mylen = 0;
  if (tid < 128) {
    int gc = wg * CC + en;
    bb0 = bias[0 * HHH + gc];
    bb1 = bias[1 * HHH + gc];
    bb2 = bias[2 * HHH + gc];
    bb3 = bias[3 * HHH + gc];
    bb4 = bias[4 * HHH + gc];
    bb5 = bias[5 * HHH + gc];
    mylen = lengths[eb];
    cbuf[tid] = 0.0f;
  }

  // Prefetch x(t=0).
  f32x4 xv[8];
#pragma unroll
  for (int i = 0; i < 8; ++i) xv[i] = *(const f32x4*)(x + xcm[i]);

  __syncthreads();

  for (int t = 0; t < TT; ++t) {
    // ---- Cheap hint spin: lane L watches flags[L] (one coalesced 512B
    // load per wave per round). flags are monotonic; h(t) ready <=> all
    // flags >= t.
    {
      const int need = t;
      int fv;
      do {
        fv = (int)__hip_atomic_load(flags + lane, __ATOMIC_RELAXED,
                                    __HIP_MEMORY_SCOPE_AGENT);
      } while (__any(fv < need));
    }

    // ---- Tagged data read: usually exactly one round (tags verify the
    // flag hint; respin covers flag-racing-ahead-of-data).
    const u64* hb = hex + (size_t)(t & 1) * 4096;
    const unsigned wtag = (unsigned)t;
    u64 w0[8], w1[8];
    for (;;) {
#pragma unroll
      for (int i = 0; i < 8; ++i) {
        w0[i] = __hip_atomic_load(hb + pidx[i], __ATOMIC_RELAXED,
                                  __HIP_MEMORY_SCOPE_AGENT);
        w1[i] = __hip_atomic_load(hb + pidx[i] + 1, __ATOMIC_RELAXED,
                                  __HIP_MEMORY_SCOPE_AGENT);
      }
      unsigned bad = 0;
#pragma unroll
      for (int i = 0; i < 8; ++i)
        bad |= ((unsigned)(w0[i] >> 32) ^ wtag) |
               ((unsigned)(w1[i] >> 32) ^ wtag);
      if (bad == 0) break;
    }

    // ---- Stage u = f16(x)+h and h into LDS (swizzled).
#pragma unroll
    for (int i = 0; i < 8; ++i) {
      f16x4 hv;
      hv[0] = h_lo(w0[i]);
      hv[1] = h_hi(w0[i]);
      hv[2] = h_lo(w1[i]);
      hv[3] = h_hi(w1[i]);
      f16x4 uv;
#pragma unroll
      for (int j = 0; j < 4; ++j) uv[j] = (f16)xv[i][j] + hv[j];
      *(f16x4*)(u_sw + soffv[i]) = uv;
      *(f16x4*)(h_sw + soffv[i]) = hv;
    }
    __syncthreads();

    // ---- MFMA: wave's 16-col tile, K=512, 4 independent chains.
    f32x4 acc0 = {0.f, 0.f, 0.f, 0.f}, acc1 = {0.f, 0.f, 0.f, 0.f};
    f32x4 acc2 = {0.f, 0.f, 0.f, 0.f}, acc3 = {0.f, 0.f, 0.f, 0.f};
    const f16* asrc = (wave < 3) ? u_sw : h_sw;
#pragma unroll
    for (int kk = 0; kk < 16; kk += 4) {
      f16x8 a0 = *(const f16x8*)(asrc + (kk * 64 + (lane ^ kk)) * 8);
      f16x8 a1 =
          *(const f16x8*)(asrc + ((kk + 1) * 64 + (lane ^ (kk + 1))) * 8);
      f16x8 a2 =
          *(const f16x8*)(asrc + ((kk + 2) * 64 + (lane ^ (kk + 2))) * 8);
      f16x8 a3 =
          *(const f16x8*)(asrc + ((kk + 3) * 64 + (lane ^ (kk + 3))) * 8);
      acc0 = __builtin_amdgcn_mfma_f32_16x16x32_f16(a0, bW[kk], acc0, 0, 0, 0);
      acc1 =
          __builtin_amdgcn_mfma_f32_16x16x32_f16(a1, bW[kk + 1], acc1, 0, 0, 0);
      acc2 =
          __builtin_amdgcn_mfma_f32_16x16x32_f16(a2, bW[kk + 2], acc2, 0, 0, 0);
      acc3 =
          __builtin_amdgcn_mfma_f32_16x16x32_f16(a3, bW[kk + 3], acc3, 0, 0, 0);
    }
#pragma unroll
    for (int r = 0; r < 4; ++r)
      gbuf[wave * 272 + (q * 4 + r) * 17 + n16] =
          (acc0[r] + acc1[r]) + (acc2[r] + acc3[r]);
    __syncthreads();

    // ---- Epilogue (fp32) + direct publish (waves 0-1; partner via shfl).
    if (tid < 128) {
      float g0 = gbuf[0 * 272 + eb * 17 + en] + 2.f * bb0;      // i
      float g1 = gbuf[0 * 272 + eb * 17 + en + 8] + 2.f * bb1;  // f
      float g2 = gbuf[1 * 272 + eb * 17 + en] + 2.f * bb2;      // m~
      float g3 = gbuf[1 * 272 + eb * 17 + en + 8] + 2.f * bb3;  // o
      float g4 = gbuf[2 * 272 + eb * 17 + en] + 2.f * bb4;      // hw
      float p5 = gbuf[2 * 272 + eb * 17 + en + 8];              // (x+h)@W5
      float qv = gbuf[3 * 272 + eb * 17 + en];                  // h@W5
      float ig = sigf(g0), fg = sigf(g1), mt = tanhfast(g2);
      float og = sigf(g3), hwv = sigf(g4);
      float pi5 = p5 - qv + bb5;
      float cold = cbuf[tid];
      float mem = ig * mt + fg * cold;
      float o1 = og * tanhfast(mem);
      float ov = hwv * o1 + (1.0f - hwv) * pi5;
      float msk = (t < mylen) ? 1.0f : 0.0f;
      ov *= msk;
      mem *= msk;
      cbuf[tid] = mem;
      out[((size_t)eb * TT + t) * HHH + wg * CC + en] = ov;

      unsigned hbits = (unsigned)__builtin_bit_cast(unsigned short, (f16)ov);
      unsigned other = (unsigned)__shfl_xor((int)hbits, 1, 64);
      if ((en & 1) == 0) {
        u64 wv = (u64)(hbits & 0xffffu) | ((u64)(other & 0xffffu) << 16) |
                 ((u64)(unsigned)(t + 1) << 32);
        __hip_atomic_store(
            hex + (size_t)((t + 1) & 1) * 4096 + eb * 256 + wg * 4 + (en >> 1),
            wv, __ATOMIC_RELAXED, __HIP_MEMORY_SCOPE_AGENT);
      }
    }

    // ---- Flag hint: issued after the data stores in program order (no
    // drain; flag may race ahead of data by sub-RT — tags verify).
    if (tid == 0)
      __hip_atomic_store(flags + wg, (unsigned)(t + 1), __ATOMIC_RELAXED,
                         __HIP_MEMORY_SCOPE_AGENT);

    // Prefetch x(t+1); latency hides under next step's flag spin.
    if (t + 1 < TT) {
#pragma unroll
      for (int i = 0; i < 8; ++i)
        xv[i] = *(const f32x4*)(x + xcm[i] + (size_t)(t + 1) * DD);
    }
    // No trailing __syncthreads: next-step staging only touches u_sw/h_sw,
    // whose step-t reads all completed before the post-MFMA barrier; gbuf
    // writes for t+1 are fenced by the next post-staging barrier, which
    // cannot be reached before this WG's own publish (poll includes own
    // columns).
  }
}

extern "C" void kernel_launch(void* const* d_in, const int* in_sizes, int n_in,
                              void* d_out, int out_size, void* d_ws,
                              size_t ws_size, hipStream_t stream) {
  (void)in_sizes;
  (void)n_in;
  (void)out_size;
  (void)ws_size;
  const float* x = (const float*)d_in[0];
  const int* lengths = (const int*)d_in[1];
  const float* W = (const float*)d_in[2];
  const float* bias = (const float*)d_in[3];
  float* out = (float*)d_out;

  u64* hex = (u64*)d_ws;                              // [2][4096] tagged pairs
  unsigned* flags = (unsigned*)((char*)d_ws + 65536);  // [NG] step flags
  hipMemsetAsync(d_ws, 0, 65536 + 256, stream);        // h0=0, tags=0, flags=0

  lstm_scan<<<dim3(NG), dim3(BLK), 0, stream>>>(x, lengths, W, bias, out, hex,
                                                flags);
}